// Round 1
// baseline (462.507 us; speedup 1.0000x reference)
//
#include <hip/hip_runtime.h>
#include <hip/hip_bf16.h>

#define TDIM 2048
#define DDIM 768
#define IDIM 2048
#define NEXP 8

typedef __bf16 v8bf __attribute__((ext_vector_type(8)));
typedef float v4f __attribute__((ext_vector_type(4)));

#define MFMA_B16(A, B, C) __builtin_amdgcn_mfma_f32_16x16x32_bf16(A, B, C, 0, 0, 0)

// XOR swizzle within a [64 rows][64 cols] bf16 tile (row stride 128 B).
static __device__ __forceinline__ int swz(int row, int colByte) {
  return row * 128 + (colByte ^ ((row & 7) << 4));
}

// ---------------- router: softmax -> top2 -> renorm, build gathered lists ----------------
__global__ __launch_bounds__(64)
void router_kernel(const float* __restrict__ x, const float* __restrict__ rw,
                   int* __restrict__ cnt, int* __restrict__ lists, float* __restrict__ wt)
{
  const int t = blockIdx.x;
  const int lane = threadIdx.x;
  const float* xp = x + (size_t)t * DDIM;
  float4 xv0 = *(const float4*)(xp + lane * 4);
  float4 xv1 = *(const float4*)(xp + 256 + lane * 4);
  float4 xv2 = *(const float4*)(xp + 512 + lane * 4);
  float logit[NEXP];
#pragma unroll
  for (int e = 0; e < NEXP; ++e) {
    const float* w = rw + (size_t)e * DDIM;
    float4 w0 = *(const float4*)(w + lane * 4);
    float4 w1 = *(const float4*)(w + 256 + lane * 4);
    float4 w2 = *(const float4*)(w + 512 + lane * 4);
    float p = xv0.x * w0.x + xv0.y * w0.y + xv0.z * w0.z + xv0.w * w0.w
            + xv1.x * w1.x + xv1.y * w1.y + xv1.z * w1.z + xv1.w * w1.w
            + xv2.x * w2.x + xv2.y * w2.y + xv2.z * w2.z + xv2.w * w2.w;
#pragma unroll
    for (int off = 32; off > 0; off >>= 1) p += __shfl_down(p, off, 64);
    logit[e] = p;
  }
  if (lane == 0) {
    float m = logit[0];
#pragma unroll
    for (int e = 1; e < NEXP; ++e) m = fmaxf(m, logit[e]);
    float pr[NEXP];
#pragma unroll
    for (int e = 0; e < NEXP; ++e) pr[e] = expf(logit[e] - m);
    int i0 = 0; float v0 = pr[0];
#pragma unroll
    for (int e = 1; e < NEXP; ++e) if (pr[e] > v0) { v0 = pr[e]; i0 = e; }
    int i1 = -1; float v1 = -1.f;
#pragma unroll
    for (int e = 0; e < NEXP; ++e) if (e != i0 && pr[e] > v1) { v1 = pr[e]; i1 = e; }
    float inv = 1.f / (v0 + v1);
    int p0 = atomicAdd(&cnt[i0], 1);
    lists[i0 * TDIM + p0] = t * 2;       // slot = t*2 + k
    wt[t * 2] = v0 * inv;
    int p1 = atomicAdd(&cnt[i1], 1);
    lists[i1 * TDIM + p1] = t * 2 + 1;
    wt[t * 2 + 1] = v1 * inv;
  }
}

// ---------------- fused gate+up GEMM (+silu*up), h out in bf16 ----------------
// out[row][i] = silu(sg * x.Wg^T) * (su * x.Wu^T); A = x rows (dense tokens or gathered)
template<bool GATHER, bool TERNARY>
__global__ __launch_bounds__(256)
void gateup_kernel(const float* __restrict__ x,
                   const float* __restrict__ wgf, const float* __restrict__ wuf,
                   const int* __restrict__ qg, const int* __restrict__ qu,
                   const float* __restrict__ scales,
                   const int* __restrict__ cnt, const int* __restrict__ lists,
                   __hip_bfloat16* __restrict__ hout)
{
  int e = 0, tm, tn, count;
  if constexpr (GATHER) {
    int b = blockIdx.x;
    tn = b & 31; tm = (b >> 5) & 31; e = b >> 10;
    count = cnt[e];
    if (tm * 64 >= count) return;
  } else {
    tn = blockIdx.x & 31; tm = blockIdx.x >> 5;
    count = TDIM;
  }

  __shared__ __align__(16) char lds[24 * 1024];
  char* As = lds;
  char* Bg = lds + 8192;
  char* Bu = lds + 16384;

  const int tid = threadIdx.x;
  const int lane = tid & 63;
  const int wid = tid >> 6;
  const int wr = wid >> 1, wc = wid & 1;
  const int lr = lane & 15;
  const int lkb = ((lane >> 4) * 8) * 2;   // byte offset of this lane's k-chunk

  const int* listE = nullptr;
  if constexpr (GATHER) listE = lists + e * TDIM;

  v4f ag[2][2] = {};
  v4f au[2][2] = {};

  for (int kt = 0; kt < DDIM / 64; ++kt) {
    const int k0 = kt * 64;
#pragma unroll
    for (int p = 0; p < 2; ++p) {
      const int r = p * 32 + (tid >> 3);
      const int c = (tid & 7) * 8;
      // ---- A (tokens) fp32 -> bf16 ----
      const int rg = tm * 64 + r;
      int tok;
      if constexpr (GATHER) tok = (rg < count) ? (listE[rg] >> 1) : 0;
      else tok = rg;
      const float* sa = x + (size_t)tok * DDIM + k0 + c;
      float4 a0 = *(const float4*)sa;
      float4 a1 = *(const float4*)(sa + 4);
      v8bf va;
      va[0] = (__bf16)a0.x; va[1] = (__bf16)a0.y; va[2] = (__bf16)a0.z; va[3] = (__bf16)a0.w;
      va[4] = (__bf16)a1.x; va[5] = (__bf16)a1.y; va[6] = (__bf16)a1.z; va[7] = (__bf16)a1.w;
      *(v8bf*)(As + swz(r, c * 2)) = va;
      // ---- B (gate & up weights) ----
      const int ng = tn * 64 + r;
      if constexpr (TERNARY) {
        const int* sg_ = qg + ((size_t)e * IDIM + ng) * DDIM + k0 + c;
        const int* su_ = qu + ((size_t)e * IDIM + ng) * DDIM + k0 + c;
        int4 g0 = *(const int4*)sg_; int4 g1 = *(const int4*)(sg_ + 4);
        int4 u0 = *(const int4*)su_; int4 u1 = *(const int4*)(su_ + 4);
        v8bf vg, vu;
        vg[0] = (__bf16)(float)g0.x; vg[1] = (__bf16)(float)g0.y;
        vg[2] = (__bf16)(float)g0.z; vg[3] = (__bf16)(float)g0.w;
        vg[4] = (__bf16)(float)g1.x; vg[5] = (__bf16)(float)g1.y;
        vg[6] = (__bf16)(float)g1.z; vg[7] = (__bf16)(float)g1.w;
        vu[0] = (__bf16)(float)u0.x; vu[1] = (__bf16)(float)u0.y;
        vu[2] = (__bf16)(float)u0.z; vu[3] = (__bf16)(float)u0.w;
        vu[4] = (__bf16)(float)u1.x; vu[5] = (__bf16)(float)u1.y;
        vu[6] = (__bf16)(float)u1.z; vu[7] = (__bf16)(float)u1.w;
        *(v8bf*)(Bg + swz(r, c * 2)) = vg;
        *(v8bf*)(Bu + swz(r, c * 2)) = vu;
      } else {
        const float* sg_ = wgf + (size_t)ng * DDIM + k0 + c;
        const float* su_ = wuf + (size_t)ng * DDIM + k0 + c;
        float4 g0 = *(const float4*)sg_; float4 g1 = *(const float4*)(sg_ + 4);
        float4 u0 = *(const float4*)su_; float4 u1 = *(const float4*)(su_ + 4);
        v8bf vg, vu;
        vg[0] = (__bf16)g0.x; vg[1] = (__bf16)g0.y; vg[2] = (__bf16)g0.z; vg[3] = (__bf16)g0.w;
        vg[4] = (__bf16)g1.x; vg[5] = (__bf16)g1.y; vg[6] = (__bf16)g1.z; vg[7] = (__bf16)g1.w;
        vu[0] = (__bf16)u0.x; vu[1] = (__bf16)u0.y; vu[2] = (__bf16)u0.z; vu[3] = (__bf16)u0.w;
        vu[4] = (__bf16)u1.x; vu[5] = (__bf16)u1.y; vu[6] = (__bf16)u1.z; vu[7] = (__bf16)u1.w;
        *(v8bf*)(Bg + swz(r, c * 2)) = vg;
        *(v8bf*)(Bu + swz(r, c * 2)) = vu;
      }
    }
    __syncthreads();
#pragma unroll
    for (int ks = 0; ks < 2; ++ks) {
      const int kb = ks * 64 + lkb;
      v8bf fa0 = *(const v8bf*)(As + swz(wr * 32 + lr,      kb));
      v8bf fa1 = *(const v8bf*)(As + swz(wr * 32 + 16 + lr, kb));
      v8bf fg0 = *(const v8bf*)(Bg + swz(wc * 32 + lr,      kb));
      v8bf fg1 = *(const v8bf*)(Bg + swz(wc * 32 + 16 + lr, kb));
      v8bf fu0 = *(const v8bf*)(Bu + swz(wc * 32 + lr,      kb));
      v8bf fu1 = *(const v8bf*)(Bu + swz(wc * 32 + 16 + lr, kb));
      ag[0][0] = MFMA_B16(fa0, fg0, ag[0][0]);
      ag[0][1] = MFMA_B16(fa0, fg1, ag[0][1]);
      ag[1][0] = MFMA_B16(fa1, fg0, ag[1][0]);
      ag[1][1] = MFMA_B16(fa1, fg1, ag[1][1]);
      au[0][0] = MFMA_B16(fa0, fu0, au[0][0]);
      au[0][1] = MFMA_B16(fa0, fu1, au[0][1]);
      au[1][0] = MFMA_B16(fa1, fu0, au[1][0]);
      au[1][1] = MFMA_B16(fa1, fu1, au[1][1]);
    }
    __syncthreads();
  }

  float sg = 1.f, su = 1.f;
  if constexpr (TERNARY) { sg = scales[e * 3 + 0]; su = scales[e * 3 + 1]; }
  const int rbase = (lane >> 4) * 4;
#pragma unroll
  for (int mi = 0; mi < 2; ++mi) {
#pragma unroll
    for (int j = 0; j < 4; ++j) {
      const int r = wr * 32 + mi * 16 + rbase + j;
      const int rg = tm * 64 + r;
      if (GATHER && rg >= count) continue;
      size_t drow;
      if constexpr (GATHER) drow = (size_t)listE[rg];
      else drow = (size_t)rg;
      __hip_bfloat16* dst = hout + drow * IDIM + tn * 64 + wc * 32 + lr;
#pragma unroll
      for (int ni = 0; ni < 2; ++ni) {
        float g = ag[mi][ni][j] * sg;
        float u = au[mi][ni][j] * su;
        float h = g / (1.f + __expf(-g)) * u;
        dst[ni * 16] = __float2bfloat16(h);
      }
    }
  }
}

// ---------------- down GEMM: out[row][d] = (h . Wd^T) * sd * gatew ----------------
template<bool GATHER, bool TERNARY>
__global__ __launch_bounds__(256)
void down_kernel(const __hip_bfloat16* __restrict__ hsrc,
                 const float* __restrict__ wdf, const int* __restrict__ qd,
                 const float* __restrict__ scales, const float* __restrict__ wt,
                 const int* __restrict__ cnt, const int* __restrict__ lists,
                 float* __restrict__ outb)
{
  int e = 0, tm, tn, count;
  if constexpr (GATHER) {
    int b = blockIdx.x;
    tn = b % 12; int b2 = b / 12; tm = b2 & 31; e = b2 >> 5;
    count = cnt[e];
    if (tm * 64 >= count) return;
  } else {
    tn = blockIdx.x % 12; tm = blockIdx.x / 12;
    count = TDIM;
  }

  __shared__ __align__(16) char lds[16 * 1024];
  char* As = lds;
  char* Bs = lds + 8192;

  const int tid = threadIdx.x;
  const int lane = tid & 63;
  const int wid = tid >> 6;
  const int wr = wid >> 1, wc = wid & 1;
  const int lr = lane & 15;
  const int lkb = ((lane >> 4) * 8) * 2;

  const int* listE = nullptr;
  if constexpr (GATHER) listE = lists + e * TDIM;

  v4f acc[2][2] = {};

  for (int kt = 0; kt < IDIM / 64; ++kt) {
    const int k0 = kt * 64;
#pragma unroll
    for (int p = 0; p < 2; ++p) {
      const int r = p * 32 + (tid >> 3);
      const int c = (tid & 7) * 8;
      // ---- A (h rows, already bf16) ----
      const int rg = tm * 64 + r;
      int srow;
      if constexpr (GATHER) srow = (rg < count) ? listE[rg] : 0;
      else srow = rg;
      v8bf va = *(const v8bf*)(hsrc + (size_t)srow * IDIM + k0 + c);
      *(v8bf*)(As + swz(r, c * 2)) = va;
      // ---- B (down weights [D][I]) ----
      const int ng = tn * 64 + r;
      if constexpr (TERNARY) {
        const int* sb = qd + ((size_t)e * DDIM + ng) * IDIM + k0 + c;
        int4 b0 = *(const int4*)sb; int4 b1 = *(const int4*)(sb + 4);
        v8bf vb;
        vb[0] = (__bf16)(float)b0.x; vb[1] = (__bf16)(float)b0.y;
        vb[2] = (__bf16)(float)b0.z; vb[3] = (__bf16)(float)b0.w;
        vb[4] = (__bf16)(float)b1.x; vb[5] = (__bf16)(float)b1.y;
        vb[6] = (__bf16)(float)b1.z; vb[7] = (__bf16)(float)b1.w;
        *(v8bf*)(Bs + swz(r, c * 2)) = vb;
      } else {
        const float* sb = wdf + (size_t)ng * IDIM + k0 + c;
        float4 b0 = *(const float4*)sb; float4 b1 = *(const float4*)(sb + 4);
        v8bf vb;
        vb[0] = (__bf16)b0.x; vb[1] = (__bf16)b0.y; vb[2] = (__bf16)b0.z; vb[3] = (__bf16)b0.w;
        vb[4] = (__bf16)b1.x; vb[5] = (__bf16)b1.y; vb[6] = (__bf16)b1.z; vb[7] = (__bf16)b1.w;
        *(v8bf*)(Bs + swz(r, c * 2)) = vb;
      }
    }
    __syncthreads();
#pragma unroll
    for (int ks = 0; ks < 2; ++ks) {
      const int kb = ks * 64 + lkb;
      v8bf fa0 = *(const v8bf*)(As + swz(wr * 32 + lr,      kb));
      v8bf fa1 = *(const v8bf*)(As + swz(wr * 32 + 16 + lr, kb));
      v8bf fb0 = *(const v8bf*)(Bs + swz(wc * 32 + lr,      kb));
      v8bf fb1 = *(const v8bf*)(Bs + swz(wc * 32 + 16 + lr, kb));
      acc[0][0] = MFMA_B16(fa0, fb0, acc[0][0]);
      acc[0][1] = MFMA_B16(fa0, fb1, acc[0][1]);
      acc[1][0] = MFMA_B16(fa1, fb0, acc[1][0]);
      acc[1][1] = MFMA_B16(fa1, fb1, acc[1][1]);
    }
    __syncthreads();
  }

  float sd = 1.f;
  if constexpr (TERNARY) sd = scales[e * 3 + 2];
  const int rbase = (lane >> 4) * 4;
#pragma unroll
  for (int mi = 0; mi < 2; ++mi) {
#pragma unroll
    for (int j = 0; j < 4; ++j) {
      const int r = wr * 32 + mi * 16 + rbase + j;
      const int rg = tm * 64 + r;
      if (GATHER && rg >= count) continue;
      float w = 1.f;
      size_t drow;
      if constexpr (GATHER) { int s = listE[rg]; drow = (size_t)s; w = wt[s]; }
      else drow = (size_t)rg;
      float* dst = outb + drow * DDIM + tn * 64 + wc * 32 + lr;
#pragma unroll
      for (int ni = 0; ni < 2; ++ni) {
        dst[ni * 16] = acc[mi][ni][j] * sd * w;
      }
    }
  }
}

// ---------------- final combine: out = shared + slot0 + slot1 (fp32 out) ----------------
__global__ __launch_bounds__(256)
void combine_kernel(const float* __restrict__ sh, const float* __restrict__ slot,
                    float* __restrict__ out)
{
  const int i4 = blockIdx.x * 256 + threadIdx.x;
  const int i0 = i4 * 4;
  const int t = i0 / DDIM;
  const int d = i0 - t * DDIM;
  float4 a = *(const float4*)(sh + i0);
  float4 b = *(const float4*)(slot + (size_t)(2 * t) * DDIM + d);
  float4 c = *(const float4*)(slot + (size_t)(2 * t + 1) * DDIM + d);
  float4 r;
  r.x = a.x + b.x + c.x;
  r.y = a.y + b.y + c.y;
  r.z = a.z + b.z + c.z;
  r.w = a.w + b.w + c.w;
  *(float4*)(out + i0) = r;
}

extern "C" void kernel_launch(void* const* d_in, const int* in_sizes, int n_in,
                              void* d_out, int out_size, void* d_ws, size_t ws_size,
                              hipStream_t stream)
{
  const float* x   = (const float*)d_in[0];
  const float* rw  = (const float*)d_in[1];
  const float* swg = (const float*)d_in[2];
  const float* swu = (const float*)d_in[3];
  const float* swd = (const float*)d_in[4];
  const int*   qg  = (const int*)d_in[5];
  const int*   qu  = (const int*)d_in[6];
  const int*   qd  = (const int*)d_in[7];
  const float* es  = (const float*)d_in[8];

  char* ws = (char*)d_ws;
  size_t off = 0;
  auto alloc = [&](size_t bytes) {
    void* p = ws + off;
    off = (off + bytes + 255) & ~(size_t)255;
    return p;
  };
  int*   cnt   = (int*)alloc(NEXP * 4);
  int*   lists = (int*)alloc((size_t)NEXP * TDIM * 4);
  float* wt    = (float*)alloc((size_t)TDIM * 2 * 4);
  __hip_bfloat16* hs = (__hip_bfloat16*)alloc((size_t)TDIM * IDIM * 2);
  __hip_bfloat16* he = (__hip_bfloat16*)alloc((size_t)TDIM * 2 * IDIM * 2);
  float* sh_out   = (float*)alloc((size_t)TDIM * DDIM * 4);
  float* slot_out = (float*)alloc((size_t)TDIM * 2 * DDIM * 4);

  hipMemsetAsync(cnt, 0, NEXP * 4, stream);
  router_kernel<<<TDIM, 64, 0, stream>>>(x, rw, cnt, lists, wt);

  // shared expert gate+up: [2048 x 2048], K=768
  gateup_kernel<false, false><<<32 * 32, 256, 0, stream>>>(
      x, swg, swu, nullptr, nullptr, es, nullptr, nullptr, hs);
  // gathered experts gate+up
  gateup_kernel<true, true><<<NEXP * 32 * 32, 256, 0, stream>>>(
      x, nullptr, nullptr, qg, qu, es, cnt, lists, he);
  // shared expert down: [2048 x 768], K=2048
  down_kernel<false, false><<<32 * 12, 256, 0, stream>>>(
      hs, swd, nullptr, es, wt, nullptr, nullptr, sh_out);
  // gathered experts down
  down_kernel<true, true><<<NEXP * 32 * 12, 256, 0, stream>>>(
      he, nullptr, qd, es, wt, cnt, lists, slot_out);

  combine_kernel<<<(TDIM * DDIM / 4) / 256, 256, 0, stream>>>(sh_out, slot_out, (float*)d_out);
}

// Round 3
// 422.943 us; speedup vs baseline: 1.0935x; 1.0935x over previous
//
#include <hip/hip_runtime.h>
#include <hip/hip_bf16.h>

#define TDIM 2048
#define DDIM 768
#define IDIM 2048
#define NEXP 8

typedef __bf16 v8bf __attribute__((ext_vector_type(8)));
typedef float v4f __attribute__((ext_vector_type(4)));

#define MFMA_B16(A,B,C) __builtin_amdgcn_mfma_f32_16x16x32_bf16(A,B,C,0,0,0)

typedef __attribute__((address_space(1))) const unsigned int* gas_t;
typedef __attribute__((address_space(3))) unsigned int* las_t;

__device__ __forceinline__ void gload16(const void* g, void* l) {
  __builtin_amdgcn_global_load_lds((gas_t)g, (las_t)l, 16, 0, 0);
}

// ---------------- router: softmax -> top2 -> renorm, build gathered lists ----------------
__global__ __launch_bounds__(64)
void router_kernel(const float* __restrict__ x, const float* __restrict__ rw,
                   int* __restrict__ cnt, int* __restrict__ lists, float* __restrict__ wt)
{
  const int t = blockIdx.x;
  const int lane = threadIdx.x;
  const float* xp = x + (size_t)t * DDIM;
  float4 xv0 = *(const float4*)(xp + lane * 4);
  float4 xv1 = *(const float4*)(xp + 256 + lane * 4);
  float4 xv2 = *(const float4*)(xp + 512 + lane * 4);
  float logit[NEXP];
#pragma unroll
  for (int e = 0; e < NEXP; ++e) {
    const float* w = rw + (size_t)e * DDIM;
    float4 w0 = *(const float4*)(w + lane * 4);
    float4 w1 = *(const float4*)(w + 256 + lane * 4);
    float4 w2 = *(const float4*)(w + 512 + lane * 4);
    float p = xv0.x * w0.x + xv0.y * w0.y + xv0.z * w0.z + xv0.w * w0.w
            + xv1.x * w1.x + xv1.y * w1.y + xv1.z * w1.z + xv1.w * w1.w
            + xv2.x * w2.x + xv2.y * w2.y + xv2.z * w2.z + xv2.w * w2.w;
#pragma unroll
    for (int off = 32; off > 0; off >>= 1) p += __shfl_down(p, off, 64);
    logit[e] = p;
  }
  if (lane == 0) {
    float m = logit[0];
#pragma unroll
    for (int e = 1; e < NEXP; ++e) m = fmaxf(m, logit[e]);
    float pr[NEXP];
#pragma unroll
    for (int e = 0; e < NEXP; ++e) pr[e] = expf(logit[e] - m);
    int i0 = 0; float v0 = pr[0];
#pragma unroll
    for (int e = 1; e < NEXP; ++e) if (pr[e] > v0) { v0 = pr[e]; i0 = e; }
    int i1 = -1; float v1 = -1.f;
#pragma unroll
    for (int e = 0; e < NEXP; ++e) if (e != i0 && pr[e] > v1) { v1 = pr[e]; i1 = e; }
    float inv = 1.f / (v0 + v1);
    int p0 = atomicAdd(&cnt[i0], 1);
    lists[i0 * TDIM + p0] = t * 2;       // slot = t*2 + k
    wt[t * 2] = v0 * inv;
    int p1 = atomicAdd(&cnt[i1], 1);
    lists[i1 * TDIM + p1] = t * 2 + 1;
    wt[t * 2 + 1] = v1 * inv;
  }
}

// ---------------- prepack: weights -> bf16, tiled [b][128 rows][64 cols], XOR-swizzled ----------------
// dst tile b = ((e*NT + nt)*KT + kt); within tile, linear byte L holds element
// (row = L/128, k = kt*64 + ((L%128) ^ ((row&7)<<4))/2). GEMM staging then reads
// dst purely sequentially via global_load_lds into a linear LDS buffer.
template<bool ISINT>
__global__ __launch_bounds__(256)
void pack_tiles_kernel(const void* __restrict__ srcv, __hip_bfloat16* __restrict__ dst,
                       int NT, int KT)
{
  const int b = blockIdx.x;
  const int kt = b % KT;
  const int nt = (b / KT) % NT;
  const int e  = b / (KT * NT);
  const int N  = NT * 128;
  const int Kk = KT * 64;
  const int tid = threadIdx.x;
  __hip_bfloat16* dbase = dst + (size_t)b * 8192;
#pragma unroll
  for (int p = 0; p < 4; ++p) {
    const int q = p * 256 + tid;
    const int row = q >> 3;
    const int cb = ((q & 7) * 16) ^ ((row & 7) << 4);
    const int k = kt * 64 + (cb >> 1);
    const size_t srcoff = ((size_t)e * N + (nt * 128 + row)) * Kk + k;
    v8bf v;
    if constexpr (ISINT) {
      const int* s = (const int*)srcv + srcoff;
      int4 a0 = *(const int4*)s;
      int4 a1 = *(const int4*)(s + 4);
      v[0] = (__bf16)(float)a0.x; v[1] = (__bf16)(float)a0.y;
      v[2] = (__bf16)(float)a0.z; v[3] = (__bf16)(float)a0.w;
      v[4] = (__bf16)(float)a1.x; v[5] = (__bf16)(float)a1.y;
      v[6] = (__bf16)(float)a1.z; v[7] = (__bf16)(float)a1.w;
    } else {
      const float* s = (const float*)srcv + srcoff;
      float4 a0 = *(const float4*)s;
      float4 a1 = *(const float4*)(s + 4);
      v[0] = (__bf16)a0.x; v[1] = (__bf16)a0.y; v[2] = (__bf16)a0.z; v[3] = (__bf16)a0.w;
      v[4] = (__bf16)a1.x; v[5] = (__bf16)a1.y; v[6] = (__bf16)a1.z; v[7] = (__bf16)a1.w;
    }
    *(v8bf*)(dbase + (size_t)q * 8) = v;
  }
}

// x fp32 -> bf16, linear row-major
__global__ __launch_bounds__(256)
void pack_x_kernel(const float* __restrict__ src, __hip_bfloat16* __restrict__ dst)
{
  const size_t i = ((size_t)blockIdx.x * 256 + threadIdx.x) * 8;
  float4 a0 = *(const float4*)(src + i);
  float4 a1 = *(const float4*)(src + i + 4);
  v8bf v;
  v[0] = (__bf16)a0.x; v[1] = (__bf16)a0.y; v[2] = (__bf16)a0.z; v[3] = (__bf16)a0.w;
  v[4] = (__bf16)a1.x; v[5] = (__bf16)a1.y; v[6] = (__bf16)a1.z; v[7] = (__bf16)a1.w;
  *(v8bf*)(dst + i) = v;
}

// ---------------- unified gate+up GEMM, 128x128 tile, BK=64, m97 structure ----------------
// blocks [0,2048): experts (e = b>>8, tm=(b>>4)&15, tn=b&15), gathered rows, out=he[slot]
// blocks [2048,2304): shared expert, dense rows, out=hs[token]
__global__ __launch_bounds__(256)
void gateup_kernel(const __hip_bfloat16* __restrict__ xb,
                   const __hip_bfloat16* __restrict__ wgT, const __hip_bfloat16* __restrict__ wuT,
                   const __hip_bfloat16* __restrict__ sgT, const __hip_bfloat16* __restrict__ suT,
                   const float* __restrict__ es,
                   const int* __restrict__ cnt, const int* __restrict__ lists,
                   __hip_bfloat16* __restrict__ he, __hip_bfloat16* __restrict__ hs)
{
  const int b = blockIdx.x;
  int tm, tn, count;
  const __hip_bfloat16 *wg, *wu;
  const int* listE = nullptr;
  __hip_bfloat16* hout;
  float sg, su;
  if (b < 2048) {
    const int e = b >> 8; tm = (b >> 4) & 15; tn = b & 15;
    count = cnt[e];
    if (tm * 128 >= count) return;
    wg = wgT + (size_t)(e * 16 + tn) * (12 * 8192);
    wu = wuT + (size_t)(e * 16 + tn) * (12 * 8192);
    listE = lists + e * TDIM;
    sg = es[e * 3 + 0]; su = es[e * 3 + 1];
    hout = he;
  } else {
    const int b2 = b - 2048; tm = b2 >> 4; tn = b2 & 15;
    count = TDIM;
    wg = sgT + (size_t)tn * (12 * 8192);
    wu = suT + (size_t)tn * (12 * 8192);
    sg = 1.f; su = 1.f;
    hout = hs;
  }

  __shared__ __align__(16) char As[16384];
  __shared__ __align__(16) char Bg[16384];
  __shared__ __align__(16) char Bu[16384];

  const int tid = threadIdx.x;
  const int lane = tid & 63;
  const int wid = tid >> 6;
  const int wr = wid >> 1, wc = wid & 1;
  const int lr16 = lane & 15, hk = lane >> 4;
  const int xorm = (lr16 & 7) << 4;

  // A staging: per-lane pre-swizzled gather source addresses (linear LDS dest)
  const int cA = (((lane & 7) ^ (lane >> 3)) << 4);
  const char* aptr[4];
#pragma unroll
  for (int p = 0; p < 4; ++p) {
    const int row = p * 32 + wid * 8 + (lane >> 3);
    const int rg = tm * 128 + row;
    int tok;
    if (listE) { const int idx = rg < count ? rg : count - 1; tok = listE[idx] >> 1; }
    else tok = rg;
    aptr[p] = (const char*)xb + (size_t)tok * (DDIM * 2) + cA;
  }
  const char* bgp = (const char*)wg + wid * 1024 + lane * 16;
  const char* bup = (const char*)wu + wid * 1024 + lane * 16;
  char* ldsA  = As + wid * 1024;
  char* ldsBg = Bg + wid * 1024;
  char* ldsBu = Bu + wid * 1024;

  v4f ag[4][4] = {};
  v4f au[4][4] = {};

  for (int kt = 0; kt < 12; ++kt) {
#pragma unroll
    for (int p = 0; p < 4; ++p) gload16(aptr[p] + kt * 128, ldsA + p * 4096);
#pragma unroll
    for (int p = 0; p < 4; ++p) gload16(bgp + kt * 16384 + p * 4096, ldsBg + p * 4096);
#pragma unroll
    for (int p = 0; p < 4; ++p) gload16(bup + kt * 16384 + p * 4096, ldsBu + p * 4096);
    __syncthreads();
#pragma unroll
    for (int ks = 0; ks < 2; ++ks) {
      const int colb = (ks * 64 + hk * 16) ^ xorm;
      v8bf fa[4];
#pragma unroll
      for (int m = 0; m < 4; ++m)
        fa[m] = *(const v8bf*)(As + (wr * 64 + m * 16 + lr16) * 128 + colb);
#pragma unroll
      for (int n = 0; n < 4; ++n) {
        v8bf fg = *(const v8bf*)(Bg + (wc * 64 + n * 16 + lr16) * 128 + colb);
        v8bf fu = *(const v8bf*)(Bu + (wc * 64 + n * 16 + lr16) * 128 + colb);
#pragma unroll
        for (int m = 0; m < 4; ++m) {
          ag[m][n] = MFMA_B16(fa[m], fg, ag[m][n]);
          au[m][n] = MFMA_B16(fa[m], fu, au[m][n]);
        }
      }
    }
    __syncthreads();
  }

  // epilogue: h = silu(g*sg) * (u*su), bf16
#pragma unroll
  for (int m = 0; m < 4; ++m) {
#pragma unroll
    for (int j = 0; j < 4; ++j) {
      const int rl = wr * 64 + m * 16 + hk * 4 + j;
      const int rg = tm * 128 + rl;
      if (rg >= count) continue;
      const size_t drow = listE ? (size_t)listE[rg] : (size_t)rg;
      __hip_bfloat16* dst = hout + drow * IDIM + tn * 128 + wc * 64 + lr16;
#pragma unroll
      for (int n = 0; n < 4; ++n) {
        const float g = ag[m][n][j] * sg;
        const float u = au[m][n][j] * su;
        const float h = g / (1.f + __expf(-g)) * u;
        dst[n * 16] = __float2bfloat16(h);
      }
    }
  }
}

// ---------------- unified down GEMM, 128x128 tile, K=2048, atomicAdd into out ----------------
// blocks [0,768): experts (e=b/96, tm=(b%96)/6, tn=b%6), A = he gathered slots
// blocks [768,864): shared expert, A = hs dense
__global__ __launch_bounds__(256)
void down_kernel(const __hip_bfloat16* __restrict__ he, const __hip_bfloat16* __restrict__ hs,
                 const __hip_bfloat16* __restrict__ wdT, const __hip_bfloat16* __restrict__ sdT,
                 const float* __restrict__ es, const float* __restrict__ wt,
                 const int* __restrict__ cnt, const int* __restrict__ lists,
                 float* __restrict__ out)
{
  const int b = blockIdx.x;
  int tm, tn, count;
  const __hip_bfloat16 *wd, *asrc;
  const int* listE = nullptr;
  float sd;
  if (b < 768) {
    const int e = b / 96; const int r = b % 96; tm = r / 6; tn = r % 6;
    count = cnt[e];
    if (tm * 128 >= count) return;
    wd = wdT + (size_t)(e * 6 + tn) * (32 * 8192);
    listE = lists + e * TDIM;
    sd = es[e * 3 + 2];
    asrc = he;
  } else {
    const int r = b - 768; tm = r / 6; tn = r % 6;
    count = TDIM;
    wd = sdT + (size_t)tn * (32 * 8192);
    sd = 1.f;
    asrc = hs;
  }

  __shared__ __align__(16) char As[16384];
  __shared__ __align__(16) char Bs[16384];

  const int tid = threadIdx.x;
  const int lane = tid & 63;
  const int wid = tid >> 6;
  const int wr = wid >> 1, wc = wid & 1;
  const int lr16 = lane & 15, hk = lane >> 4;
  const int xorm = (lr16 & 7) << 4;

  const int cA = (((lane & 7) ^ (lane >> 3)) << 4);
  const char* aptr[4];
#pragma unroll
  for (int p = 0; p < 4; ++p) {
    const int row = p * 32 + wid * 8 + (lane >> 3);
    const int rg = tm * 128 + row;
    int srow;
    if (listE) { const int idx = rg < count ? rg : count - 1; srow = listE[idx]; }
    else srow = rg;
    aptr[p] = (const char*)asrc + (size_t)srow * (IDIM * 2) + cA;
  }
  const char* bp = (const char*)wd + wid * 1024 + lane * 16;
  char* ldsA = As + wid * 1024;
  char* ldsB = Bs + wid * 1024;

  v4f acc[4][4] = {};

  for (int kt = 0; kt < 32; ++kt) {
#pragma unroll
    for (int p = 0; p < 4; ++p) gload16(aptr[p] + kt * 128, ldsA + p * 4096);
#pragma unroll
    for (int p = 0; p < 4; ++p) gload16(bp + kt * 16384 + p * 4096, ldsB + p * 4096);
    __syncthreads();
#pragma unroll
    for (int ks = 0; ks < 2; ++ks) {
      const int colb = (ks * 64 + hk * 16) ^ xorm;
      v8bf fa[4];
#pragma unroll
      for (int m = 0; m < 4; ++m)
        fa[m] = *(const v8bf*)(As + (wr * 64 + m * 16 + lr16) * 128 + colb);
#pragma unroll
      for (int n = 0; n < 4; ++n) {
        v8bf fb = *(const v8bf*)(Bs + (wc * 64 + n * 16 + lr16) * 128 + colb);
#pragma unroll
        for (int m = 0; m < 4; ++m) acc[m][n] = MFMA_B16(fa[m], fb, acc[m][n]);
      }
    }
    __syncthreads();
  }

#pragma unroll
  for (int m = 0; m < 4; ++m) {
#pragma unroll
    for (int j = 0; j < 4; ++j) {
      const int rl = wr * 64 + m * 16 + hk * 4 + j;
      const int rg = tm * 128 + rl;
      if (rg >= count) continue;
      int tok; float w;
      if (listE) { const int slot = listE[rg]; tok = slot >> 1; w = wt[slot] * sd; }
      else { tok = rg; w = 1.f; }
      float* dst = out + (size_t)tok * DDIM + tn * 128 + wc * 64 + lr16;
#pragma unroll
      for (int n = 0; n < 4; ++n) atomicAdd(dst + n * 16, acc[m][n][j] * w);
    }
  }
}

extern "C" void kernel_launch(void* const* d_in, const int* in_sizes, int n_in,
                              void* d_out, int out_size, void* d_ws, size_t ws_size,
                              hipStream_t stream)
{
  const float* x   = (const float*)d_in[0];
  const float* rw  = (const float*)d_in[1];
  const float* swg = (const float*)d_in[2];
  const float* swu = (const float*)d_in[3];
  const float* swd = (const float*)d_in[4];
  const int*   qg  = (const int*)d_in[5];
  const int*   qu  = (const int*)d_in[6];
  const int*   qd  = (const int*)d_in[7];
  const float* es  = (const float*)d_in[8];
  float* out = (float*)d_out;

  char* ws = (char*)d_ws;
  size_t off = 0;
  auto alloc = [&](size_t bytes) { void* p = ws + off; off = (off + bytes + 255) & ~(size_t)255; return p; };
  // total ws usage ~= 114 MB
  int*   cnt   = (int*)alloc(NEXP * 4);
  int*   lists = (int*)alloc((size_t)NEXP * TDIM * 4);
  float* wt    = (float*)alloc((size_t)2 * TDIM * 4);
  __hip_bfloat16* xb  = (__hip_bfloat16*)alloc((size_t)TDIM * DDIM * 2);
  __hip_bfloat16* wgT = (__hip_bfloat16*)alloc((size_t)NEXP * 16 * 12 * 8192 * 2);
  __hip_bfloat16* wuT = (__hip_bfloat16*)alloc((size_t)NEXP * 16 * 12 * 8192 * 2);
  __hip_bfloat16* wdT = (__hip_bfloat16*)alloc((size_t)NEXP * 6 * 32 * 8192 * 2);
  __hip_bfloat16* sgT = (__hip_bfloat16*)alloc((size_t)16 * 12 * 8192 * 2);
  __hip_bfloat16* suT = (__hip_bfloat16*)alloc((size_t)16 * 12 * 8192 * 2);
  __hip_bfloat16* sdT = (__hip_bfloat16*)alloc((size_t)6 * 32 * 8192 * 2);
  __hip_bfloat16* hs  = (__hip_bfloat16*)alloc((size_t)TDIM * IDIM * 2);
  __hip_bfloat16* he  = (__hip_bfloat16*)alloc((size_t)2 * TDIM * IDIM * 2);

  hipMemsetAsync(cnt, 0, NEXP * 4, stream);
  hipMemsetAsync(out, 0, (size_t)TDIM * DDIM * 4, stream);

  router_kernel<<<TDIM, 64, 0, stream>>>(x, rw, cnt, lists, wt);
  pack_x_kernel<<<(TDIM * DDIM) / 2048, 256, 0, stream>>>(x, xb);
  pack_tiles_kernel<true><<<NEXP * 16 * 12, 256, 0, stream>>>(qg, wgT, 16, 12);
  pack_tiles_kernel<true><<<NEXP * 16 * 12, 256, 0, stream>>>(qu, wuT, 16, 12);
  pack_tiles_kernel<true><<<NEXP * 6 * 32, 256, 0, stream>>>(qd, wdT, 6, 32);
  pack_tiles_kernel<false><<<16 * 12, 256, 0, stream>>>(swg, sgT, 16, 12);
  pack_tiles_kernel<false><<<16 * 12, 256, 0, stream>>>(swu, suT, 16, 12);
  pack_tiles_kernel<false><<<6 * 32, 256, 0, stream>>>(swd, sdT, 6, 32);

  gateup_kernel<<<2048 + 256, 256, 0, stream>>>(xb, wgT, wuT, sgT, suT, es, cnt, lists, he, hs);
  down_kernel<<<768 + 96, 256, 0, stream>>>(he, hs, wdT, sdT, es, wt, cnt, lists, out);
}

// Round 4
// 369.356 us; speedup vs baseline: 1.2522x; 1.1451x over previous
//
#include <hip/hip_runtime.h>
#include <hip/hip_bf16.h>

#define TDIM 2048
#define DDIM 768
#define IDIM 2048
#define NEXP 8

typedef __bf16 v8bf __attribute__((ext_vector_type(8)));
typedef float v4f __attribute__((ext_vector_type(4)));

#define MFMA_B16(A,B,C) __builtin_amdgcn_mfma_f32_16x16x32_bf16(A,B,C,0,0,0)

typedef __attribute__((address_space(1))) const unsigned int* gas_t;
typedef __attribute__((address_space(3))) unsigned int* las_t;

__device__ __forceinline__ void gload16(const void* g, void* l) {
  __builtin_amdgcn_global_load_lds((gas_t)g, (las_t)l, 16, 0, 0);
}

// ---------------- router: softmax -> top2 -> renorm, build gathered lists ----------------
__global__ __launch_bounds__(64)
void router_kernel(const float* __restrict__ x, const float* __restrict__ rw,
                   int* __restrict__ cnt, int* __restrict__ lists, float* __restrict__ wt)
{
  const int t = blockIdx.x;
  const int lane = threadIdx.x;
  const float* xp = x + (size_t)t * DDIM;
  float4 xv0 = *(const float4*)(xp + lane * 4);
  float4 xv1 = *(const float4*)(xp + 256 + lane * 4);
  float4 xv2 = *(const float4*)(xp + 512 + lane * 4);
  float logit[NEXP];
#pragma unroll
  for (int e = 0; e < NEXP; ++e) {
    const float* w = rw + (size_t)e * DDIM;
    float4 w0 = *(const float4*)(w + lane * 4);
    float4 w1 = *(const float4*)(w + 256 + lane * 4);
    float4 w2 = *(const float4*)(w + 512 + lane * 4);
    float p = xv0.x * w0.x + xv0.y * w0.y + xv0.z * w0.z + xv0.w * w0.w
            + xv1.x * w1.x + xv1.y * w1.y + xv1.z * w1.z + xv1.w * w1.w
            + xv2.x * w2.x + xv2.y * w2.y + xv2.z * w2.z + xv2.w * w2.w;
#pragma unroll
    for (int off = 32; off > 0; off >>= 1) p += __shfl_down(p, off, 64);
    logit[e] = p;
  }
  if (lane == 0) {
    float m = logit[0];
#pragma unroll
    for (int e = 1; e < NEXP; ++e) m = fmaxf(m, logit[e]);
    float pr[NEXP];
#pragma unroll
    for (int e = 0; e < NEXP; ++e) pr[e] = expf(logit[e] - m);
    int i0 = 0; float v0 = pr[0];
#pragma unroll
    for (int e = 1; e < NEXP; ++e) if (pr[e] > v0) { v0 = pr[e]; i0 = e; }
    int i1 = -1; float v1 = -1.f;
#pragma unroll
    for (int e = 0; e < NEXP; ++e) if (e != i0 && pr[e] > v1) { v1 = pr[e]; i1 = e; }
    float inv = 1.f / (v0 + v1);
    int p0 = atomicAdd(&cnt[i0], 1);
    lists[i0 * TDIM + p0] = t * 2;       // slot = t*2 + k
    wt[t * 2] = v0 * inv;
    int p1 = atomicAdd(&cnt[i1], 1);
    lists[i1 * TDIM + p1] = t * 2 + 1;
    wt[t * 2 + 1] = v1 * inv;
  }
}

// ---------------- merged prepack: all weights -> bf16 swizzled tiles, plus x -> bf16 ----------------
// Tile layout: tile = [nt-th 128-row strip][kt-th 64-col strip], 8192 elems; linear byte L
// holds element (row = L/128, colbyte = (L%128) ^ ((row&7)<<4), k = kt*64 + colbyte/2).
// GEMM stages a 64-row half-strip (contiguous 8KB) linearly via global_load_lds.
__global__ __launch_bounds__(256)
void pack_all_kernel(const int* __restrict__ qg, const int* __restrict__ qu,
                     const int* __restrict__ qd,
                     const float* __restrict__ sg, const float* __restrict__ su,
                     const float* __restrict__ sd, const float* __restrict__ x,
                     __hip_bfloat16* __restrict__ wgT, __hip_bfloat16* __restrict__ wuT,
                     __hip_bfloat16* __restrict__ wdT, __hip_bfloat16* __restrict__ sgT,
                     __hip_bfloat16* __restrict__ suT, __hip_bfloat16* __restrict__ sdT,
                     __hip_bfloat16* __restrict__ xb)
{
  const int b = blockIdx.x;
  const int tid = threadIdx.x;
  if (b >= 5184) {  // ---- x fp32 -> bf16, linear ----
    const size_t i = (size_t)(b - 5184) * 2048 + tid * 8;
    float4 a0 = *(const float4*)(x + i);
    float4 a1 = *(const float4*)(x + i + 4);
    v8bf v;
    v[0] = (__bf16)a0.x; v[1] = (__bf16)a0.y; v[2] = (__bf16)a0.z; v[3] = (__bf16)a0.w;
    v[4] = (__bf16)a1.x; v[5] = (__bf16)a1.y; v[6] = (__bf16)a1.z; v[7] = (__bf16)a1.w;
    *(v8bf*)(xb + i) = v;
    return;
  }
  const void* src; __hip_bfloat16* dst; int NT, KT, isint, tile;
  if (b < 1536)      { src = qg; dst = wgT; NT = 16; KT = 12; isint = 1; tile = b; }
  else if (b < 3072) { src = qu; dst = wuT; NT = 16; KT = 12; isint = 1; tile = b - 1536; }
  else if (b < 4608) { src = qd; dst = wdT; NT = 6;  KT = 32; isint = 1; tile = b - 3072; }
  else if (b < 4800) { src = sg; dst = sgT; NT = 16; KT = 12; isint = 0; tile = b - 4608; }
  else if (b < 4992) { src = su; dst = suT; NT = 16; KT = 12; isint = 0; tile = b - 4800; }
  else               { src = sd; dst = sdT; NT = 6;  KT = 32; isint = 0; tile = b - 4992; }
  const int kt = tile % KT;
  const int nt = (tile / KT) % NT;
  const int e  = tile / (KT * NT);
  const int N  = NT * 128;
  const int Kk = KT * 64;
  __hip_bfloat16* dbase = dst + (size_t)tile * 8192;
#pragma unroll
  for (int p = 0; p < 4; ++p) {
    const int q = p * 256 + tid;
    const int row = q >> 3;
    const int cb = ((q & 7) * 16) ^ ((row & 7) << 4);
    const int k = kt * 64 + (cb >> 1);
    const size_t srcoff = ((size_t)e * N + (nt * 128 + row)) * Kk + k;
    v8bf v;
    if (isint) {
      const int* s = (const int*)src + srcoff;
      int4 a0 = *(const int4*)s;
      int4 a1 = *(const int4*)(s + 4);
      v[0] = (__bf16)(float)a0.x; v[1] = (__bf16)(float)a0.y;
      v[2] = (__bf16)(float)a0.z; v[3] = (__bf16)(float)a0.w;
      v[4] = (__bf16)(float)a1.x; v[5] = (__bf16)(float)a1.y;
      v[6] = (__bf16)(float)a1.z; v[7] = (__bf16)(float)a1.w;
    } else {
      const float* s = (const float*)src + srcoff;
      float4 a0 = *(const float4*)s;
      float4 a1 = *(const float4*)(s + 4);
      v[0] = (__bf16)a0.x; v[1] = (__bf16)a0.y; v[2] = (__bf16)a0.z; v[3] = (__bf16)a0.w;
      v[4] = (__bf16)a1.x; v[5] = (__bf16)a1.y; v[6] = (__bf16)a1.z; v[7] = (__bf16)a1.w;
    }
    *(v8bf*)(dbase + (size_t)q * 8) = v;
  }
}

// ---------------- unified gate+up GEMM, 128x64 tile, BK=64 ----------------
// blocks [0,4096): experts (e=b>>9, tm=(b>>5)&15, tn=b&31), gathered rows, out=he[slot]
// blocks [4096,4608): shared expert, dense rows, out=hs[token]
// 4 waves (2x2): per-wave output 64x32 -> acc 2x[4][2] = 64 regs; LDS 32KB; 3 waves/EU.
__global__ __launch_bounds__(256, 3)
void gateup_kernel(const __hip_bfloat16* __restrict__ xb,
                   const __hip_bfloat16* __restrict__ wgT, const __hip_bfloat16* __restrict__ wuT,
                   const __hip_bfloat16* __restrict__ sgT, const __hip_bfloat16* __restrict__ suT,
                   const float* __restrict__ es,
                   const int* __restrict__ cnt, const int* __restrict__ lists,
                   __hip_bfloat16* __restrict__ he, __hip_bfloat16* __restrict__ hs)
{
  const int b = blockIdx.x;
  int tm, tn, count;
  const char *wg, *wu;
  const int* listE = nullptr;
  __hip_bfloat16* hout;
  float sg, su;
  if (b < 4096) {
    const int e = b >> 9; tm = (b >> 5) & 15; tn = b & 31;
    count = cnt[e];
    if (tm * 128 >= count) return;
    const size_t base = (size_t)(e * 16 + (tn >> 1)) * (12 * 16384) + (tn & 1) * 8192;
    wg = (const char*)wgT + base;
    wu = (const char*)wuT + base;
    listE = lists + e * TDIM;
    sg = es[e * 3 + 0]; su = es[e * 3 + 1];
    hout = he;
  } else {
    const int b2 = b - 4096; tm = b2 >> 5; tn = b2 & 31;
    count = TDIM;
    const size_t base = (size_t)(tn >> 1) * (12 * 16384) + (tn & 1) * 8192;
    wg = (const char*)sgT + base;
    wu = (const char*)suT + base;
    sg = 1.f; su = 1.f;
    hout = hs;
  }

  __shared__ __align__(16) char As[16384];
  __shared__ __align__(16) char Bg[8192];
  __shared__ __align__(16) char Bu[8192];

  const int tid = threadIdx.x;
  const int lane = tid & 63;
  const int wid = tid >> 6;
  const int wr = wid >> 1, wc = wid & 1;
  const int lr16 = lane & 15, hk = lane >> 4;

  // A staging: per-lane pre-swizzled gather source addresses (linear LDS dest)
  const int cA = (((lane & 7) ^ (lane >> 3)) << 4);
  const char* aptr[4];
#pragma unroll
  for (int p = 0; p < 4; ++p) {
    const int row = p * 32 + wid * 8 + (lane >> 3);
    const int rg = tm * 128 + row;
    int tok;
    if (listE) { const int idx = rg < count ? rg : count - 1; tok = listE[idx] >> 1; }
    else tok = rg;
    aptr[p] = (const char*)xb + (size_t)tok * (DDIM * 2) + cA;
  }
  const char* bgp = wg + wid * 1024 + lane * 16;
  const char* bup = wu + wid * 1024 + lane * 16;
  char* ldsA  = As + wid * 1024;
  char* ldsBg = Bg + wid * 1024;
  char* ldsBu = Bu + wid * 1024;

  v4f ag[4][2] = {};
  v4f au[4][2] = {};

  for (int kt = 0; kt < 12; ++kt) {
#pragma unroll
    for (int p = 0; p < 4; ++p) gload16(aptr[p] + kt * 128, ldsA + p * 4096);
#pragma unroll
    for (int p = 0; p < 2; ++p) gload16(bgp + kt * 16384 + p * 4096, ldsBg + p * 4096);
#pragma unroll
    for (int p = 0; p < 2; ++p) gload16(bup + kt * 16384 + p * 4096, ldsBu + p * 4096);
    __syncthreads();
#pragma unroll
    for (int ks = 0; ks < 2; ++ks) {
      const int colb = ks * 64 + hk * 16;
      v8bf fa[4];
#pragma unroll
      for (int m = 0; m < 4; ++m) {
        const int r = wr * 64 + m * 16 + lr16;
        fa[m] = *(const v8bf*)(As + r * 128 + (colb ^ ((r & 7) << 4)));
      }
#pragma unroll
      for (int n = 0; n < 2; ++n) {
        const int r = wc * 32 + n * 16 + lr16;
        const int sb = r * 128 + (colb ^ ((r & 7) << 4));
        v8bf fg = *(const v8bf*)(Bg + sb);
        v8bf fu = *(const v8bf*)(Bu + sb);
#pragma unroll
        for (int m = 0; m < 4; ++m) {
          ag[m][n] = MFMA_B16(fa[m], fg, ag[m][n]);
          au[m][n] = MFMA_B16(fa[m], fu, au[m][n]);
        }
      }
    }
    __syncthreads();
  }

  // epilogue: h = silu(g*sg) * (u*su), bf16
#pragma unroll
  for (int m = 0; m < 4; ++m) {
#pragma unroll
    for (int j = 0; j < 4; ++j) {
      const int rl = wr * 64 + m * 16 + hk * 4 + j;
      const int rg = tm * 128 + rl;
      if (rg >= count) continue;
      const size_t drow = listE ? (size_t)listE[rg] : (size_t)rg;
      __hip_bfloat16* dst = hout + drow * IDIM + tn * 64 + wc * 32 + lr16;
#pragma unroll
      for (int n = 0; n < 2; ++n) {
        const float g = ag[m][n][j] * sg;
        const float u = au[m][n][j] * su;
        const float h = g / (1.f + __expf(-g)) * u;
        dst[n * 16] = __float2bfloat16(h);
      }
    }
  }
}

// ---------------- unified down GEMM, 128x64 tile, K=2048, atomicAdd into out ----------------
// blocks [0,1536): experts (e=b/192, tm=(b%192)/12, tn=b%12), A = he gathered slots
// blocks [1536,1728): shared expert, A = hs dense
__global__ __launch_bounds__(256, 4)
void down_kernel(const __hip_bfloat16* __restrict__ he, const __hip_bfloat16* __restrict__ hs,
                 const __hip_bfloat16* __restrict__ wdT, const __hip_bfloat16* __restrict__ sdT,
                 const float* __restrict__ es, const float* __restrict__ wt,
                 const int* __restrict__ cnt, const int* __restrict__ lists,
                 float* __restrict__ out)
{
  const int b = blockIdx.x;
  int tm, tn, count;
  const char* wd;
  const __hip_bfloat16* asrc;
  const int* listE = nullptr;
  float sd;
  if (b < 1536) {
    const int e = b / 192; const int r = b % 192; tm = r / 12; tn = r % 12;
    count = cnt[e];
    if (tm * 128 >= count) return;
    wd = (const char*)wdT + (size_t)(e * 6 + (tn >> 1)) * (32 * 16384) + (tn & 1) * 8192;
    listE = lists + e * TDIM;
    sd = es[e * 3 + 2];
    asrc = he;
  } else {
    const int r = b - 1536; tm = r / 12; tn = r % 12;
    count = TDIM;
    wd = (const char*)sdT + (size_t)(tn >> 1) * (32 * 16384) + (tn & 1) * 8192;
    sd = 1.f;
    asrc = hs;
  }

  __shared__ __align__(16) char As[16384];
  __shared__ __align__(16) char Bs[8192];

  const int tid = threadIdx.x;
  const int lane = tid & 63;
  const int wid = tid >> 6;
  const int wr = wid >> 1, wc = wid & 1;
  const int lr16 = lane & 15, hk = lane >> 4;

  const int cA = (((lane & 7) ^ (lane >> 3)) << 4);
  const char* aptr[4];
#pragma unroll
  for (int p = 0; p < 4; ++p) {
    const int row = p * 32 + wid * 8 + (lane >> 3);
    const int rg = tm * 128 + row;
    int srow;
    if (listE) { const int idx = rg < count ? rg : count - 1; srow = listE[idx]; }
    else srow = rg;
    aptr[p] = (const char*)asrc + (size_t)srow * (IDIM * 2) + cA;
  }
  const char* bp = wd + wid * 1024 + lane * 16;
  char* ldsA = As + wid * 1024;
  char* ldsB = Bs + wid * 1024;

  v4f acc[4][2] = {};

  for (int kt = 0; kt < 32; ++kt) {
#pragma unroll
    for (int p = 0; p < 4; ++p) gload16(aptr[p] + kt * 128, ldsA + p * 4096);
#pragma unroll
    for (int p = 0; p < 2; ++p) gload16(bp + kt * 16384 + p * 4096, ldsB + p * 4096);
    __syncthreads();
#pragma unroll
    for (int ks = 0; ks < 2; ++ks) {
      const int colb = ks * 64 + hk * 16;
      v8bf fa[4];
#pragma unroll
      for (int m = 0; m < 4; ++m) {
        const int r = wr * 64 + m * 16 + lr16;
        fa[m] = *(const v8bf*)(As + r * 128 + (colb ^ ((r & 7) << 4)));
      }
#pragma unroll
      for (int n = 0; n < 2; ++n) {
        const int r = wc * 32 + n * 16 + lr16;
        v8bf fb = *(const v8bf*)(Bs + r * 128 + (colb ^ ((r & 7) << 4)));
#pragma unroll
        for (int m = 0; m < 4; ++m) acc[m][n] = MFMA_B16(fa[m], fb, acc[m][n]);
      }
    }
    __syncthreads();
  }

#pragma unroll
  for (int m = 0; m < 4; ++m) {
#pragma unroll
    for (int j = 0; j < 4; ++j) {
      const int rl = wr * 64 + m * 16 + hk * 4 + j;
      const int rg = tm * 128 + rl;
      if (rg >= count) continue;
      int tok; float w;
      if (listE) { const int slot = listE[rg]; tok = slot >> 1; w = wt[slot] * sd; }
      else { tok = rg; w = 1.f; }
      float* dst = out + (size_t)tok * DDIM + tn * 64 + wc * 32 + lr16;
#pragma unroll
      for (int n = 0; n < 2; ++n) atomicAdd(dst + n * 16, acc[m][n][j] * w);
    }
  }
}

extern "C" void kernel_launch(void* const* d_in, const int* in_sizes, int n_in,
                              void* d_out, int out_size, void* d_ws, size_t ws_size,
                              hipStream_t stream)
{
  const float* x   = (const float*)d_in[0];
  const float* rw  = (const float*)d_in[1];
  const float* swg = (const float*)d_in[2];
  const float* swu = (const float*)d_in[3];
  const float* swd = (const float*)d_in[4];
  const int*   qg  = (const int*)d_in[5];
  const int*   qu  = (const int*)d_in[6];
  const int*   qd  = (const int*)d_in[7];
  const float* es  = (const float*)d_in[8];
  float* out = (float*)d_out;

  char* ws = (char*)d_ws;
  size_t off = 0;
  auto alloc = [&](size_t bytes) { void* p = ws + off; off = (off + bytes + 255) & ~(size_t)255; return p; };
  // total ws usage ~= 112 MB
  int*   cnt   = (int*)alloc(NEXP * 4);
  int*   lists = (int*)alloc((size_t)NEXP * TDIM * 4);
  float* wt    = (float*)alloc((size_t)2 * TDIM * 4);
  __hip_bfloat16* xb  = (__hip_bfloat16*)alloc((size_t)TDIM * DDIM * 2);
  __hip_bfloat16* wgT = (__hip_bfloat16*)alloc((size_t)NEXP * 16 * 12 * 8192 * 2);
  __hip_bfloat16* wuT = (__hip_bfloat16*)alloc((size_t)NEXP * 16 * 12 * 8192 * 2);
  __hip_bfloat16* wdT = (__hip_bfloat16*)alloc((size_t)NEXP * 6 * 32 * 8192 * 2);
  __hip_bfloat16* sgT = (__hip_bfloat16*)alloc((size_t)16 * 12 * 8192 * 2);
  __hip_bfloat16* suT = (__hip_bfloat16*)alloc((size_t)16 * 12 * 8192 * 2);
  __hip_bfloat16* sdT = (__hip_bfloat16*)alloc((size_t)6 * 32 * 8192 * 2);
  __hip_bfloat16* hs  = (__hip_bfloat16*)alloc((size_t)TDIM * IDIM * 2);
  __hip_bfloat16* he  = (__hip_bfloat16*)alloc((size_t)2 * TDIM * IDIM * 2);

  hipMemsetAsync(cnt, 0, NEXP * 4, stream);
  hipMemsetAsync(out, 0, (size_t)TDIM * DDIM * 4, stream);

  router_kernel<<<TDIM, 64, 0, stream>>>(x, rw, cnt, lists, wt);
  pack_all_kernel<<<5184 + 768, 256, 0, stream>>>(qg, qu, qd, swg, swu, swd, x,
                                                  wgT, wuT, wdT, sgT, suT, sdT, xb);

  gateup_kernel<<<4096 + 512, 256, 0, stream>>>(xb, wgT, wuT, sgT, suT, es, cnt, lists, he, hs);
  down_kernel<<<1536 + 192, 256, 0, stream>>>(he, hs, wdT, sdT, es, wt, cnt, lists, out);
}